// Round 1
// baseline (115.430 us; speedup 1.0000x reference)
//
#include <hip/hip_runtime.h>
#include <math.h>

#define DT_STEP (1.0f / 120.0f)
#define G_ACC 9.81f
#define K_SIGN 100.0f

__global__ void zero_out_kernel(float* out) { out[0] = 0.0f; }

__global__ __launch_bounds__(64) void ekf_kernel(
    const float* __restrict__ params,
    const float* __restrict__ cp,
    const float* __restrict__ init_state,
    const float* __restrict__ meas,
    float* __restrict__ out,
    int N, int T)
{
    const int n = blockIdx.x * blockDim.x + threadIdx.x;
    float local = 0.0f;

    if (n < N) {
        const float fric = fabsf(params[0]);
        const float damp = fabsf(params[1]);
        const float R0 = expf(cp[0]);
        const float R1 = expf(cp[1]);
        const float R2 = expf(cp[2]);
        const float Q01 = expf(cp[3]);   // diag 0,1
        const float Q23 = expf(cp[4]);   // diag 2,3
        const float Q4  = expf(cp[5]);
        const float Q5  = expf(cp[6]);

        float x[6];
#pragma unroll
        for (int i = 0; i < 6; i++) x[i] = init_state[n * 6 + i];

        float P[6][6];
#pragma unroll
        for (int i = 0; i < 6; i++)
#pragma unroll
            for (int j = 0; j < 6; j++) P[i][j] = (i == j) ? 0.01f : 0.0f;

        const float* zrow = meas + (size_t)n * T * 3;

        const float a55 = 1.0f - DT_STEP * damp;
        const float PI15 = 4.7123889803846899f;   // 1.5*pi
        const float TWOPI = 6.2831853071795865f;

        for (int t = 0; t < T; t++) {
            const float z0 = zrow[3 * t + 0];
            const float z1 = zrow[3 * t + 1];
            const float z2 = zrow[3 * t + 2];

            // ---- predict ----
            const float t0 = tanhf(K_SIGN * x[2]);
            const float t1 = tanhf(K_SIGN * x[3]);
            float xp[6];
            xp[0] = x[0] + DT_STEP * x[2];
            xp[1] = x[1] + DT_STEP * x[3];
            xp[2] = x[2] - DT_STEP * (damp * x[2] + fric * G_ACC * t0);
            xp[3] = x[3] - DT_STEP * (damp * x[3] + fric * G_ACC * t1);
            xp[4] = x[4] + DT_STEP * x[5];
            xp[5] = x[5] - DT_STEP * damp * x[5];

            const float dv0 = 1.0f - DT_STEP * (damp + fric * G_ACC * K_SIGN * (1.0f - t0 * t0));
            const float dv1 = 1.0f - DT_STEP * (damp + fric * G_ACC * K_SIGN * (1.0f - t1 * t1));

            // ---- P_pred = F P F^T + Q  (F sparse: I + DT at (0,2),(1,3),(4,5); diag dv0,dv1,a55 at 2,3,5) ----
            float M[6][6];  // M = F P
#pragma unroll
            for (int j = 0; j < 6; j++) {
                M[0][j] = P[0][j] + DT_STEP * P[2][j];
                M[1][j] = P[1][j] + DT_STEP * P[3][j];
                M[2][j] = dv0 * P[2][j];
                M[3][j] = dv1 * P[3][j];
                M[4][j] = P[4][j] + DT_STEP * P[5][j];
                M[5][j] = a55 * P[5][j];
            }
            float Pp[6][6]; // Pp = M F^T
#pragma unroll
            for (int i = 0; i < 6; i++) {
                Pp[i][0] = M[i][0] + DT_STEP * M[i][2];
                Pp[i][1] = M[i][1] + DT_STEP * M[i][3];
                Pp[i][2] = dv0 * M[i][2];
                Pp[i][3] = dv1 * M[i][3];
                Pp[i][4] = M[i][4] + DT_STEP * M[i][5];
                Pp[i][5] = a55 * M[i][5];
            }
            Pp[0][0] += Q01; Pp[1][1] += Q01;
            Pp[2][2] += Q23; Pp[3][3] += Q23;
            Pp[4][4] += Q4;  Pp[5][5] += Q5;

            // ---- innovation (midx = 0,1,4) with angle wrap on component 2 ----
            float y0 = z0 - xp[0];
            float y1 = z1 - xp[1];
            float y2 = z2 - xp[4];
            if (y2 > PI15) y2 -= TWOPI;
            else if (y2 < -PI15) y2 += TWOPI;

            // ---- S = Pp[midx,midx] + R; invert 3x3 via adjugate ----
            const float S00 = Pp[0][0] + R0, S01 = Pp[0][1], S02 = Pp[0][4];
            const float S10 = Pp[1][0], S11 = Pp[1][1] + R1, S12 = Pp[1][4];
            const float S20 = Pp[4][0], S21 = Pp[4][1], S22 = Pp[4][4] + R2;

            const float c00 = S11 * S22 - S12 * S21;
            const float c01 = S12 * S20 - S10 * S22;
            const float c02 = S10 * S21 - S11 * S20;
            const float det = S00 * c00 + S01 * c01 + S02 * c02;
            const float invdet = 1.0f / det;

            const float i00 = c00 * invdet;
            const float i01 = (S02 * S21 - S01 * S22) * invdet;
            const float i02 = (S01 * S12 - S02 * S11) * invdet;
            const float i10 = c01 * invdet;
            const float i11 = (S00 * S22 - S02 * S20) * invdet;
            const float i12 = (S02 * S10 - S00 * S12) * invdet;
            const float i20 = c02 * invdet;
            const float i21 = (S01 * S20 - S00 * S21) * invdet;
            const float i22 = (S00 * S11 - S01 * S10) * invdet;

            // ---- K = Pp[:, midx] @ Sinv  (6x3) ----
            float Km[6][3];
#pragma unroll
            for (int i = 0; i < 6; i++) {
                const float a = Pp[i][0], b = Pp[i][1], c = Pp[i][4];
                Km[i][0] = a * i00 + b * i10 + c * i20;
                Km[i][1] = a * i01 + b * i11 + c * i21;
                Km[i][2] = a * i02 + b * i12 + c * i22;
            }

            // ---- state update ----
#pragma unroll
            for (int i = 0; i < 6; i++)
                x[i] = xp[i] + Km[i][0] * y0 + Km[i][1] * y1 + Km[i][2] * y2;

            // ---- P_new = (I - K H) Pp :  P[i][j] = Pp[i][j] - sum_k K[i][k] * Pp[midx_k][j] ----
#pragma unroll
            for (int i = 0; i < 6; i++) {
#pragma unroll
                for (int j = 0; j < 6; j++) {
                    P[i][j] = Pp[i][j] - (Km[i][0] * Pp[0][j] + Km[i][1] * Pp[1][j] + Km[i][2] * Pp[4][j]);
                }
            }

            // ---- loss: logdet + mahalanobis ----
            const float maha =
                y0 * (i00 * y0 + i01 * y1 + i02 * y2) +
                y1 * (i10 * y0 + i11 * y1 + i12 * y2) +
                y2 * (i20 * y0 + i21 * y1 + i22 * y2);
            local += logf(fabsf(det)) + maha;
        }
        local *= 0.5f;
    }

    // ---- reduce across wave (block = 1 wave of 64) + atomic ----
#pragma unroll
    for (int off = 32; off > 0; off >>= 1)
        local += __shfl_down(local, off, 64);

    if ((threadIdx.x & 63) == 0) {
        atomicAdd(out, local / (float)N);
    }
}

extern "C" void kernel_launch(void* const* d_in, const int* in_sizes, int n_in,
                              void* d_out, int out_size, void* d_ws, size_t ws_size,
                              hipStream_t stream) {
    const float* params     = (const float*)d_in[0];
    const float* cov_params = (const float*)d_in[1];
    const float* init_state = (const float*)d_in[2];
    const float* meas       = (const float*)d_in[3];
    float* out = (float*)d_out;

    const int N = in_sizes[2] / 6;
    const int T = in_sizes[3] / (N * 3);

    zero_out_kernel<<<1, 1, 0, stream>>>(out);

    const int block = 64;
    const int grid = (N + block - 1) / block;
    ekf_kernel<<<grid, block, 0, stream>>>(params, cov_params, init_state, meas, out, N, T);
}

// Round 2
// 81.174 us; speedup vs baseline: 1.4220x; 1.4220x over previous
//
#include <hip/hip_runtime.h>
#include <math.h>

#define DT_STEP (1.0f / 120.0f)
#define G_ACC 9.81f
#define KS 100.0f

__global__ void zero_out_kernel(float* out) { out[0] = 0.0f; }

// One independent 2x2 Kalman filter with scalar measurement of state 0.
// FT=0: (pos_x, vel_x), FT=1: (pos_y, vel_y)  -- nonlinear friction on vel
// FT=2: (theta, omega)                        -- linear, angle-wrapped innovation
template <int FT>
__device__ __forceinline__ float run_filter(
    const float fric, const float damp,
    const float R, const float Qp, const float Qv,
    float s0, float s1,
    const float* __restrict__ zp, int T)
{
    const float fG = fric * G_ACC;
    const float a55 = 1.0f - DT_STEP * damp;
    const float PI15 = 4.7123889803846899f;
    const float TWOPI = 6.2831853071795865f;

    // P = [[a, b], [b, c]]
    float a = 0.01f, b = 0.0f, c = 0.01f;
    float loss = 0.0f;

    // rolling 2-deep prefetch of the measurement component (stride 3 floats)
    float z_cur = zp[0];
    float z_n1 = (T > 1) ? zp[3] : zp[0];

    for (int t = 0; t < T; t++) {
        const float z = z_cur;
        z_cur = z_n1;
        int tn = t + 2; if (tn > T - 1) tn = T - 1;
        z_n1 = zp[3 * tn];

        // ---- predict ----
        float s0p, s1p, dv;
        if constexpr (FT < 2) {
            // tanh(KS*s1) = 1 - 2/(exp(2*KS*s1)+1)  (saturates to +-1 cleanly)
            const float e = __expf(2.0f * KS * s1);
            const float th = 1.0f - 2.0f / (e + 1.0f);
            s0p = s0 + DT_STEP * s1;
            s1p = s1 - DT_STEP * (damp * s1 + fG * th);
            dv = 1.0f - DT_STEP * (damp + fG * KS * (1.0f - th * th));
        } else {
            s0p = s0 + DT_STEP * s1;
            s1p = a55 * s1;
            dv = a55;
        }

        // ---- P_pred = F P F^T + Q, F = [[1, DT],[0, dv]] ----
        const float M00 = a + DT_STEP * b;
        const float M01 = b + DT_STEP * c;
        const float Pp00 = M00 + DT_STEP * M01 + Qp;
        const float Pp01 = dv * M01;
        const float Pp11 = dv * dv * c + Qv;

        // ---- innovation ----
        float y = z - s0p;
        if constexpr (FT == 2) {
            if (y > PI15) y -= TWOPI;
            else if (y < -PI15) y += TWOPI;
        }

        // ---- scalar-measurement update ----
        const float S = Pp00 + R;
        const float Si = 1.0f / S;
        const float K0 = Pp00 * Si;
        const float K1 = Pp01 * Si;

        s0 = s0p + K0 * y;
        s1 = s1p + K1 * y;

        const float omk = 1.0f - K0;
        a = Pp00 * omk;
        b = Pp01 * omk;
        c = Pp11 - K1 * Pp01;

        // ---- loss contribution ----
        loss += __logf(S) + y * y * Si;
    }
    return loss;
}

__global__ __launch_bounds__(64) void ekf_split_kernel(
    const float* __restrict__ params,
    const float* __restrict__ cp,
    const float* __restrict__ init_state,
    const float* __restrict__ meas,
    float* __restrict__ out,
    int N, int T)
{
    const int n = blockIdx.x * 64 + threadIdx.x;
    const int ft = blockIdx.y;  // wave-uniform filter type
    float local = 0.0f;

    if (n < N) {
        const float fric = fabsf(params[0]);
        const float damp = fabsf(params[1]);
        const float* base = init_state + (size_t)n * 6;
        const float* zbase = meas + (size_t)n * T * 3;

        if (ft == 0) {
            const float R = __expf(cp[0]);
            const float Qp = __expf(cp[3]);
            const float Qv = __expf(cp[4]);
            local = run_filter<0>(fric, damp, R, Qp, Qv, base[0], base[2], zbase + 0, T);
        } else if (ft == 1) {
            const float R = __expf(cp[1]);
            const float Qp = __expf(cp[3]);
            const float Qv = __expf(cp[4]);
            local = run_filter<1>(fric, damp, R, Qp, Qv, base[1], base[3], zbase + 1, T);
        } else {
            const float R = __expf(cp[2]);
            const float Qp = __expf(cp[5]);
            const float Qv = __expf(cp[6]);
            local = run_filter<2>(fric, damp, R, Qp, Qv, base[4], base[5], zbase + 2, T);
        }
    }

    // wave-level reduction (block = 1 wave of 64) then one atomic per block
#pragma unroll
    for (int off = 32; off > 0; off >>= 1)
        local += __shfl_down(local, off, 64);

    if ((threadIdx.x & 63) == 0) {
        atomicAdd(out, local * 0.5f / (float)N);
    }
}

extern "C" void kernel_launch(void* const* d_in, const int* in_sizes, int n_in,
                              void* d_out, int out_size, void* d_ws, size_t ws_size,
                              hipStream_t stream) {
    const float* params     = (const float*)d_in[0];
    const float* cov_params = (const float*)d_in[1];
    const float* init_state = (const float*)d_in[2];
    const float* meas       = (const float*)d_in[3];
    float* out = (float*)d_out;

    const int N = in_sizes[2] / 6;
    const int T = in_sizes[3] / (N * 3);

    zero_out_kernel<<<1, 1, 0, stream>>>(out);

    dim3 grid(N / 64, 3);
    ekf_split_kernel<<<grid, 64, 0, stream>>>(params, cov_params, init_state, meas, out, N, T);
}